// Round 16
// baseline (164.124 us; speedup 1.0000x reference)
//
#include <hip/hip_runtime.h>
#include <cstddef>

typedef short short8 __attribute__((ext_vector_type(8)));
typedef unsigned short ushort8 __attribute__((ext_vector_type(8)));
typedef float f32x4 __attribute__((ext_vector_type(4)));

#define AS1(p) ((const __attribute__((address_space(1))) void*)(p))
#define AS3(p) ((__attribute__((address_space(3))) void*)(p))

__device__ __forceinline__ unsigned short f2bf(float f) {
  unsigned int u = __builtin_bit_cast(unsigned int, f);
  u += 0x7FFFu + ((u >> 16) & 1u);   // round-to-nearest-even
  return (unsigned short)(u >> 16);
}

__device__ __forceinline__ void gload_lds16(const void* g, void* l) {
  __builtin_amdgcn_global_load_lds(AS1(g), AS3(l), 16, 0, 0);
}

template <int N>
__device__ __forceinline__ void vwait() {
  asm volatile("s_waitcnt vmcnt(%0)" :: "n"(N) : "memory");
}

// ---------------------------------------------------------------------------
// Fused prep (ONE dispatch): W1 transpose+cvt, W2 transpose+cvt, X f32->bf16.
// (round-9 verified)
// ---------------------------------------------------------------------------
__global__ __launch_bounds__(256)
void prep_fused(const float* __restrict__ X,
                const float* __restrict__ W1,
                const float* __restrict__ W2,
                unsigned short* __restrict__ Xbf,
                unsigned short* __restrict__ W1t,
                unsigned short* __restrict__ W2t) {
  const int b   = blockIdx.x;
  const int tid = threadIdx.x;

  if (b >= 8192) {   // ---- X cvt ----
    const size_t i = (size_t)(b - 8192) * 256 + tid;   // 0 .. 2^21-1
    float4 v = *reinterpret_cast<const float4*>(X + i * 4);
    ushort4 o;
    o.x = f2bf(v.x); o.y = f2bf(v.y); o.z = f2bf(v.z); o.w = f2bf(v.w);
    *reinterpret_cast<ushort4*>(Xbf + i * 4) = o;
    return;
  }

  __shared__ float tile[32][33];
  const float* in;
  unsigned short* out;
  int Kd, Nd, n0, k0;
  if (b < 4096) {              // W1: Kd=1024 (H), Nd=4096 (I)
    in = W1; out = W1t; Kd = 1024; Nd = 4096;
    n0 = (b & 127) * 32;
    k0 = (b >> 7) * 32;
  } else {                     // W2: Kd=4096 (I), Nd=1024 (H)
    const int b2 = b - 4096;
    in = W2; out = W2t; Kd = 4096; Nd = 1024;
    n0 = (b2 & 31) * 32;
    k0 = (b2 >> 5) * 32;
  }
  const int tx = tid & 31;
  const int ty = tid >> 5;
#pragma unroll
  for (int i = 0; i < 4; ++i)
    tile[ty + i * 8][tx] = in[(size_t)(k0 + ty + i * 8) * Nd + n0 + tx];
  __syncthreads();
#pragma unroll
  for (int i = 0; i < 4; ++i)
    out[(size_t)(n0 + ty + i * 8) * Kd + k0 + tx] = f2bf(tile[tx][ty + i * 8]);
}

// ---------------------------------------------------------------------------
// Standalone prep kernels (fallback path only).
// ---------------------------------------------------------------------------
__global__ void cvt_f32_bf16(const float* __restrict__ in,
                             unsigned short* __restrict__ out, int n4) {
  int i = blockIdx.x * blockDim.x + threadIdx.x;
  if (i >= n4) return;
  float4 v = *reinterpret_cast<const float4*>(in + (size_t)i * 4);
  ushort4 o;
  o.x = f2bf(v.x); o.y = f2bf(v.y); o.z = f2bf(v.z); o.w = f2bf(v.w);
  *reinterpret_cast<ushort4*>(out + (size_t)i * 4) = o;
}

__global__ void transpose_cvt(const float* __restrict__ in,
                              unsigned short* __restrict__ out,
                              int Kd, int Nd) {
  __shared__ float tile[32][33];
  const int n0 = blockIdx.x * 32;
  const int k0 = blockIdx.y * 32;
  const int tx = threadIdx.x;
  const int ty = threadIdx.y;
#pragma unroll
  for (int i = 0; i < 4; ++i)
    tile[ty + i * 8][tx] = in[(size_t)(k0 + ty + i * 8) * Nd + n0 + tx];
  __syncthreads();
#pragma unroll
  for (int i = 0; i < 4; ++i)
    out[(size_t)(n0 + ty + i * 8) * Kd + k0 + tx] = f2bf(tile[tx][ty + i * 8]);
}

// ---------------------------------------------------------------------------
// QUADRANT-PHASE GEMM + RACE-FREE READ-AHEAD (round-16):
// r13 quadrant structure, but each phase's fragment ds_reads are issued at
// the END of the PRIOR phase (post-MFMA, pre-barrier), targeting halves
// guaranteed by the vwait+barrier pair ONE PHASE EARLIER — so when any wave
// issues a read, every wave has provably passed the vwait covering its own
// staging loads for that half (the r14 race — reading after only one's OWN
// vwait — is structurally excluded). ds_read latency hides under the
// stage-issue + vwait + barrier-join instead of sitting before the MFMAs.
// Wait schedule (re-derived, in-order vmcnt): P1 vwait<LA> => A1(d) done;
// P2 none; P3 vwait<LB> => A0(e),B0(e) done; P4 vwait<LA> => B1(e) done.
// Reads: P1end->B1(d)->bF[1]; P2end->A1(d)->aF1; P4end->A0,B0(e)->aF0,bF[0].
// Static register banks: aF0 (P1,P2), aF1 (P3,P4), bF[QN] — each write
// lands in a bank last used >=1 phase ago. lgkmcnt(0)+sched_barrier(0) at
// phase open (rule #18). WAR on LDS: stages overwrite regions last read
// >=5 phases / 4 barriers earlier. Swizzle + bounce epilogue unchanged.
// ---------------------------------------------------------------------------
#define QP3(QM, QN, AF, RDNEXT, STAGE, WAITC)                                  \
  {                                                                            \
    asm volatile("s_waitcnt lgkmcnt(0)" ::: "memory");                         \
    __builtin_amdgcn_sched_barrier(0);                                         \
    __builtin_amdgcn_s_setprio(1);                                             \
    _Pragma("unroll")                                                          \
    for (int mi = 0; mi < 4; ++mi)                                             \
      _Pragma("unroll")                                                        \
      for (int ni = 0; ni < NF; ++ni)                                          \
        _Pragma("unroll")                                                      \
        for (int kk = 0; kk < 2; ++kk)                                         \
          acc[QM][QN][mi][ni] = __builtin_amdgcn_mfma_f32_16x16x32_bf16(       \
              AF[mi][kk], bF[QN][ni][kk], acc[QM][QN][mi][ni], 0, 0, 0);       \
    __builtin_amdgcn_s_setprio(0);                                             \
    RDNEXT;                                                                    \
    STAGE;                                                                     \
    WAITC;                                                                     \
    __builtin_amdgcn_sched_barrier(0);                                         \
    __builtin_amdgcn_s_barrier();                                              \
  }

template <int BN, int RELU_BF16_OUT>
__global__ __launch_bounds__(512, 2)
void gemm_q3(const unsigned short* __restrict__ A, int lda,
             const unsigned short* __restrict__ B, int ldb,
             const float* __restrict__ bias,
             void* __restrict__ C, int ldc, int K, int nbx) {
  constexpr int NF  = BN / 128;        // B frags per wave per quadrant (2/1)
  constexpr int LA  = 2;               // loads/thread per A-half stage
  constexpr int LB  = BN / 128;        // loads/thread per B-half stage (2/1)
  constexpr int BHB = BN * 64;         // bytes per B half-buffer (16K/8K)
  extern __shared__ char lds[];

  const int tid  = threadIdx.x;
  const int lane = tid & 63;
  const int wid  = tid >> 6;
  const int wm2  = wid >> 2;   // 0..1 (64-row slice within 128-row quadrant)
  const int wn4  = wid & 3;    // 0..3 (col slice within quadrant)

  // bijective XCD-chunked swizzle (grid % 8 == 0)
  const int cpx     = gridDim.x >> 3;
  const int logical = (blockIdx.x & 7) * cpx + (blockIdx.x >> 3);
  const int m0 = (logical / nbx) * 256;
  const int n0 = (logical % nbx) * BN;

  f32x4 acc[2][2][4][NF];
#pragma unroll
  for (int a = 0; a < 2; ++a)
#pragma unroll
    for (int b = 0; b < 2; ++b)
#pragma unroll
      for (int c = 0; c < 4; ++c)
#pragma unroll
        for (int d = 0; d < NF; ++d)
          acc[a][b][c][d] = (f32x4){0.f, 0.f, 0.f, 0.f};

  // stage maps: linear LDS dest, pre-swizzled global source.
  size_t aG[2], bG[2];
#pragma unroll
  for (int u = 0; u < 2; ++u) {
    const int s   = (u * 512 + tid) * 16;
    const int nat = s ^ (((s >> 7) & 7) << 4);
    aG[u] = (size_t)(m0 + (nat >> 7)) * lda + ((nat & 127) >> 1);
    if (u < LB)
      bG[u] = (size_t)(n0 + (nat >> 7)) * ldb + ((nat & 127) >> 1);
    else
      bG[u] = 0;
  }
  const int wb0 = (tid & 448) * 16;    // wave-uniform base (+lane*16 by HW)
  const int wb1 = 8192 + wb0;

  auto stageA = [&](int d, int h, int kel) {
    char* dst = lds + d * 32768 + h * 16384;
    gload_lds16(A + aG[0] + (size_t)h * 128 * lda + kel, dst + wb0);
    gload_lds16(A + aG[1] + (size_t)h * 128 * lda + kel, dst + wb1);
  };
  auto stageB = [&](int d, int h, int kel) {
    char* dst = lds + 65536 + d * 2 * BHB + h * BHB;
    gload_lds16(B + bG[0] + (size_t)h * (BN / 2) * ldb + kel, dst + wb0);
    if constexpr (LB == 2)
      gload_lds16(B + bG[1] + (size_t)h * (BN / 2) * ldb + kel, dst + wb1);
  };

  // swizzled ds_read offsets (within one half-buffer)
  int ardA[4][2], brdB[NF][2];
#pragma unroll
  for (int mi = 0; mi < 4; ++mi)
#pragma unroll
    for (int kk = 0; kk < 2; ++kk) {
      const int nat = (wm2 * 64 + mi * 16 + (lane & 15)) * 128 +
                      kk * 64 + (lane >> 4) * 16;
      ardA[mi][kk] = nat ^ (((nat >> 7) & 7) << 4);
    }
#pragma unroll
  for (int ni = 0; ni < NF; ++ni)
#pragma unroll
    for (int kk = 0; kk < 2; ++kk) {
      const int nat = (wn4 * (BN / 8) + ni * 16 + (lane & 15)) * 128 +
                      kk * 64 + (lane >> 4) * 16;
      brdB[ni][kk] = nat ^ (((nat >> 7) & 7) << 4);
    }

  // fragment register banks: aF0 (QM=0), aF1 (QM=1), bF[QN]
  short8 aF0[4][2], aF1[4][2];
  short8 bF[2][NF][2];

  auto rdB1 = [&](int dd) {            // B1(dd) -> bF[1]
    char* bb = lds + 65536 + dd * 2 * BHB + BHB;
#pragma unroll
    for (int ni = 0; ni < NF; ++ni)
#pragma unroll
      for (int kk = 0; kk < 2; ++kk)
        bF[1][ni][kk] = *reinterpret_cast<const short8*>(bb + brdB[ni][kk]);
  };
  auto rdA1 = [&](int dd) {            // A1(dd) -> aF1
    char* ab = lds + dd * 32768 + 16384;
#pragma unroll
    for (int mi = 0; mi < 4; ++mi)
#pragma unroll
      for (int kk = 0; kk < 2; ++kk)
        aF1[mi][kk] = *reinterpret_cast<const short8*>(ab + ardA[mi][kk]);
  };
  auto rdAB0 = [&](int ee) {           // A0(ee) -> aF0, B0(ee) -> bF[0]
    char* ab = lds + ee * 32768;
#pragma unroll
    for (int mi = 0; mi < 4; ++mi)
#pragma unroll
      for (int kk = 0; kk < 2; ++kk)
        aF0[mi][kk] = *reinterpret_cast<const short8*>(ab + ardA[mi][kk]);
    char* bb = lds + 65536 + ee * 2 * BHB;
#pragma unroll
    for (int ni = 0; ni < NF; ++ni)
#pragma unroll
      for (int kk = 0; kk < 2; ++kk)
        bF[0][ni][kk] = *reinterpret_cast<const short8*>(bb + brdB[ni][kk]);
  };

  // prologue: tile 0 halves [A0,B0,B1,A1]; vwait<LA> drains A0,B0,B1 (A1 in
  // flight); barrier (collective guarantee); pre-read P1's fragments.
  stageA(0, 0, 0);
  stageB(0, 0, 0);
  stageB(0, 1, 0);
  stageA(0, 1, 0);
  vwait<LA>();
  __builtin_amdgcn_s_barrier();
  rdAB0(0);

  const int NT = K >> 6;
  for (int it = 0; it < NT - 1; ++it) {
    const int d = it & 1, e = d ^ 1;
    const int nk = (it + 1) << 6;
    QP3(0, 0, aF0, rdB1(d),   stageA(e, 0, nk), vwait<LA>());
    QP3(0, 1, aF0, rdA1(d),   stageB(e, 0, nk), ((void)0));
    QP3(1, 0, aF1, ((void)0), stageB(e, 1, nk), vwait<LB>());
    QP3(1, 1, aF1, rdAB0(e),  stageA(e, 1, nk), vwait<LA>());
  }
  {
    const int d = (NT - 1) & 1;
    QP3(0, 0, aF0, rdB1(d),   ((void)0), vwait<0>());
    QP3(0, 1, aF0, rdA1(d),   ((void)0), ((void)0));
    QP3(1, 0, aF1, ((void)0), ((void)0), ((void)0));
    QP3(1, 1, aF1, ((void)0), ((void)0), ((void)0));
  }

  // ---- Coalesced epilogue via LDS bounce (r12, verified) -----------------
  __syncthreads();
  {
#pragma unroll
    for (int qm = 0; qm < 2; ++qm) {
#pragma unroll
      for (int qn = 0; qn < 2; ++qn) {
#pragma unroll
        for (int ni = 0; ni < NF; ++ni) {
          const int c = qn * (BN / 2) + wn4 * (BN / 8) + ni * 16 + (lane & 15);
          const float bv = bias[n0 + c];
#pragma unroll
          for (int mi = 0; mi < 4; ++mi) {
#pragma unroll
            for (int rr = 0; rr < 4; ++rr) {
              const int row = qm * 128 + wm2 * 64 + mi * 16 +
                              (lane >> 4) * 4 + rr;
              float v = acc[qm][qn][mi][ni][rr] + bv;
              if (RELU_BF16_OUT) {
                v = v > 0.f ? v : 0.f;
                const int byte = (row * 512 + c * 2) ^ ((row & 7) << 4);
                *reinterpret_cast<unsigned short*>(lds + byte) = f2bf(v);
              } else {
                const int byte = (row * 512 + c * 4) ^ ((row & 7) << 4);
                *reinterpret_cast<float*>(lds + byte) = v;
              }
            }
          }
        }
      }
    }
    __syncthreads();
#pragma unroll
    for (int i = 0; i < 16; ++i) {
      const int idx  = i * 512 + tid;        // 0..8191
      const int row  = idx >> 5;
      const int g    = idx & 31;
      const int byte = (row * 512 + g * 16) ^ ((row & 7) << 4);
      const uint4 val = *reinterpret_cast<const uint4*>(lds + byte);
      if (RELU_BF16_OUT) {
        unsigned short* dst = (unsigned short*)C +
            (size_t)(m0 + row) * ldc + n0 + g * 8;
        *reinterpret_cast<uint4*>(dst) = val;
      } else {
        float* dst = (float*)C + (size_t)(m0 + row) * ldc + n0 + g * 4;
        *reinterpret_cast<uint4*>(dst) = val;
      }
    }
  }
}

// ---------------------------------------------------------------------------
// Fallback 128^2 GEMM (round-2, verified) for small-ws configurations.
// ---------------------------------------------------------------------------
template <int A_F32, int RELU_BF16_OUT>
__global__ __launch_bounds__(256, 2)
void gemm_bf16(const void* __restrict__ Ap, int lda,
               const unsigned short* __restrict__ B, int ldb,
               const float* __restrict__ bias,
               void* __restrict__ C, int ldc,
               int K, int beta) {
  __shared__ char lds[32768];
  char* const As = lds;
  char* const Bs = lds + 16384;

  const int tid  = threadIdx.x;
  const int lane = tid & 63;
  const int w    = tid >> 6;
  const int wm   = w >> 1;
  const int wn   = w & 1;
  const int m0   = blockIdx.y * 128;
  const int n0   = blockIdx.x * 128;

  f32x4 acc[4][4];
#pragma unroll
  for (int i = 0; i < 4; ++i)
#pragma unroll
    for (int j = 0; j < 4; ++j)
      acc[i][j] = (f32x4){0.f, 0.f, 0.f, 0.f};

  int srow[4], scol[4], sbase[4];
#pragma unroll
  for (int j = 0; j < 4; ++j) {
    const int stored  = (j * 256 + tid) * 16;
    const int natural = stored ^ (((stored >> 7) & 7) << 4);
    srow[j]  = natural >> 7;
    scol[j]  = (natural & 127) >> 1;
    sbase[j] = (j * 256 + (tid & 192)) * 16;
  }

  size_t agofs[4];
  int ast[4];
  if (A_F32) {
#pragma unroll
    for (int pq = 0; pq < 4; ++pq) {
      const int idx = pq * 256 + tid;
      const int rr  = idx >> 3;
      const int kbe = (idx & 7) * 8;
      agofs[pq] = (size_t)(m0 + rr) * lda + kbe;
      const int nat = rr * 128 + kbe * 2;
      ast[pq] = nat ^ (((nat >> 7) & 7) << 4);
    }
  }

  const int nsteps = K >> 6;
  for (int ks = 0; ks < nsteps; ++ks) {
    const int k0 = ks << 6;
    if (A_F32) {
      const float* Af = (const float*)Ap;
#pragma unroll
      for (int pq = 0; pq < 4; ++pq) {
        const float* sp = Af + agofs[pq] + k0;
        float4 x0 = *reinterpret_cast<const float4*>(sp);
        float4 x1 = *reinterpret_cast<const float4*>(sp + 4);
        ushort8 v;
        v[0] = f2bf(x0.x); v[1] = f2bf(x0.y); v[2] = f2bf(x0.z); v[3] = f2bf(x0.w);
        v[4] = f2bf(x1.x); v[5] = f2bf(x1.y); v[6] = f2bf(x1.z); v[7] = f2bf(x1.w);
        *reinterpret_cast<ushort8*>(As + ast[pq]) = v;
      }
    } else {
      const unsigned short* Ab = (const unsigned short*)Ap;
#pragma unroll
      for (int j = 0; j < 4; ++j)
        gload_lds16(Ab + (size_t)(m0 + srow[j]) * lda + (k0 + scol[j]),
                    As + sbase[j]);
    }
#pragma unroll
    for (int j = 0; j < 4; ++j)
      gload_lds16(B + (size_t)(n0 + srow[j]) * ldb + (k0 + scol[j]),
                  Bs + sbase[j]);
    __syncthreads();

#pragma unroll
    for (int kk = 0; kk < 2; ++kk) {
      const int kb = kk * 64 + (lane >> 4) * 16;
      short8 af[4], bfv[4];
#pragma unroll
      for (int mi = 0; mi < 4; ++mi) {
        int nat = (wm * 64 + mi * 16 + (lane & 15)) * 128 + kb;
        int st  = nat ^ (((nat >> 7) & 7) << 4);
        af[mi] = *reinterpret_cast<const short8*>(As + st);
      }
#pragma unroll
      for (int ni = 0; ni < 4; ++ni) {
        int nat = (wn * 64 + ni * 16 + (lane & 15)) * 128 + kb;
        int st  = nat ^ (((nat >> 7) & 7) << 4);
        bfv[ni] = *reinterpret_cast<const short8*>(Bs + st);
      }
#pragma unroll
      for (int mi = 0; mi < 4; ++mi)
#pragma unroll
        for (int ni = 0; ni < 4; ++ni)
          acc[mi][ni] = __builtin_amdgcn_mfma_f32_16x16x32_bf16(
              af[mi], bfv[ni], acc[mi][ni], 0, 0, 0);
    }
    __syncthreads();
  }

  const int row0 = m0 + wm * 64 + (lane >> 4) * 4;
  const int col0 = n0 + wn * 64 + (lane & 15);
#pragma unroll
  for (int ni = 0; ni < 4; ++ni) {
    const int c = col0 + ni * 16;
    const float bv = beta ? 0.f : bias[c];
#pragma unroll
    for (int mi = 0; mi < 4; ++mi) {
#pragma unroll
      for (int rr = 0; rr < 4; ++rr) {
        const size_t idx = (size_t)(row0 + mi * 16 + rr) * ldc + c;
        float v = acc[mi][ni][rr] + bv;
        if (RELU_BF16_OUT) {
          v = v > 0.f ? v : 0.f;
          ((unsigned short*)C)[idx] = f2bf(v);
        } else {
          if (beta) v += ((float*)C)[idx];
          ((float*)C)[idx] = v;
        }
      }
    }
  }
}

// ---------------------------------------------------------------------------
extern "C" void kernel_launch(void* const* d_in, const int* in_sizes, int n_in,
                              void* d_out, int out_size, void* d_ws, size_t ws_size,
                              hipStream_t stream) {
  const float* X  = (const float*)d_in[0];  // [8192][1024]
  const float* W1 = (const float*)d_in[1];  // [1024][4096]
  const float* b1 = (const float*)d_in[2];  // [4096]
  const float* W2 = (const float*)d_in[3];  // [4096][1024]
  const float* b2 = (const float*)d_in[4];  // [1024]
  float* out = (float*)d_out;               // [8192][1024] f32

  const int M = 8192, H = 1024, I = 4096;
  const size_t MB = 1024 * 1024;

  char* ws = (char*)d_ws;
  unsigned short* W1t = (unsigned short*)ws;            // [I][H] bf16, 8 MB
  unsigned short* W2t = (unsigned short*)(ws + 8 * MB); // [H][I] bf16, 8 MB

  if (ws_size >= 80 * MB) {
    // Fast path. Xbf parked in d_out tail (fully consumed by L1 before the
    // single L2 dispatch writes d_out; stream-serialized).
    unsigned short* Xbf = (unsigned short*)((char*)d_out + 16 * MB);
    unsigned short* Hbf = (unsigned short*)(ws + 16 * MB);   // [M][I] bf16
    prep_fused<<<16384, 256, 0, stream>>>(X, W1, W2, Xbf, W1t, W2t);
    // L1: Hbf = relu(X*W1+b1). quadrant+read-ahead 256x256, grid 512.
    gemm_q3<256, 1><<<512, 512, 131072, stream>>>(
        Xbf, H, W1t, H, b1, Hbf, I, H, I / 256);
    // L2: out = Hbf*W2+b2. quadrant+read-ahead 256x128, grid 256.
    gemm_q3<128, 0><<<256, 512, 131072, stream>>>(
        Hbf, I, W2t, I, b2, out, H, I, H / 128);
    return;
  }

  // Fallback: adaptive chunked path (round-2 verified kernels).
  transpose_cvt<<<dim3(I / 32, H / 32), dim3(32, 8), 0, stream>>>(W1, W1t, H, I);
  transpose_cvt<<<dim3(H / 32, I / 32), dim3(32, 8), 0, stream>>>(W2, W2t, I, H);

  int Ic, useXbf;
  unsigned short* Xbf = nullptr;
  unsigned short* Hc;
  if (ws_size >= 64 * MB) {
    Ic = 2048; useXbf = 1;
    Xbf = (unsigned short*)(ws + 16 * MB);
    Hc  = (unsigned short*)(ws + 32 * MB);
  } else if (ws_size >= 48 * MB) {
    Ic = 1024; useXbf = 1;
    Xbf = (unsigned short*)(ws + 16 * MB);
    Hc  = (unsigned short*)(ws + 32 * MB);
  } else if (ws_size >= 32 * MB) {
    Ic = 1024; useXbf = 0;
    Hc  = (unsigned short*)(ws + 16 * MB);
  } else if (ws_size >= 24 * MB) {
    Ic = 512;  useXbf = 0;
    Hc  = (unsigned short*)(ws + 16 * MB);
  } else if (ws_size >= 20 * MB) {
    Ic = 256;  useXbf = 0;
    Hc  = (unsigned short*)(ws + 16 * MB);
  } else {
    Ic = 128;  useXbf = 0;
    Hc  = (unsigned short*)(ws + 16 * MB);
  }

  if (useXbf) {
    int n4 = (M * H) / 4;
    cvt_f32_bf16<<<(n4 + 255) / 256, 256, 0, stream>>>(X, Xbf, n4);
  }

  const int nch = I / Ic;
  for (int c = 0; c < nch; ++c) {
    const int i0 = c * Ic;
    if (useXbf)
      gemm_bf16<0, 1><<<dim3(Ic / 128, M / 128), 256, 0, stream>>>(
          Xbf, H, W1t + (size_t)i0 * H, H, b1 + i0, Hc, Ic, H, 0);
    else
      gemm_bf16<1, 1><<<dim3(Ic / 128, M / 128), 256, 0, stream>>>(
          X, H, W1t + (size_t)i0 * H, H, b1 + i0, Hc, Ic, H, 0);
    gemm_bf16<0, 0><<<dim3(H / 128, M / 128), 256, 0, stream>>>(
        Hc, Ic, W2t + i0, I, b2, out, H, Ic, c > 0);
  }
}

// Round 17
// 157.117 us; speedup vs baseline: 1.0446x; 1.0446x over previous
//
#include <hip/hip_runtime.h>
#include <cstddef>

typedef short short8 __attribute__((ext_vector_type(8)));
typedef unsigned short ushort8 __attribute__((ext_vector_type(8)));
typedef float f32x4 __attribute__((ext_vector_type(4)));

#define AS1(p) ((const __attribute__((address_space(1))) void*)(p))
#define AS3(p) ((__attribute__((address_space(3))) void*)(p))

__device__ __forceinline__ unsigned short f2bf(float f) {
  unsigned int u = __builtin_bit_cast(unsigned int, f);
  u += 0x7FFFu + ((u >> 16) & 1u);   // round-to-nearest-even
  return (unsigned short)(u >> 16);
}

__device__ __forceinline__ void gload_lds16(const void* g, void* l) {
  __builtin_amdgcn_global_load_lds(AS1(g), AS3(l), 16, 0, 0);
}

template <int N>
__device__ __forceinline__ void vwait() {
  asm volatile("s_waitcnt vmcnt(%0)" :: "n"(N) : "memory");
}

// ---------------------------------------------------------------------------
// Fused prep (ONE dispatch): W1 transpose+cvt, W2 transpose+cvt, X f32->bf16.
// (round-9 verified)
// ---------------------------------------------------------------------------
__global__ __launch_bounds__(256)
void prep_fused(const float* __restrict__ X,
                const float* __restrict__ W1,
                const float* __restrict__ W2,
                unsigned short* __restrict__ Xbf,
                unsigned short* __restrict__ W1t,
                unsigned short* __restrict__ W2t) {
  const int b   = blockIdx.x;
  const int tid = threadIdx.x;

  if (b >= 8192) {   // ---- X cvt ----
    const size_t i = (size_t)(b - 8192) * 256 + tid;   // 0 .. 2^21-1
    float4 v = *reinterpret_cast<const float4*>(X + i * 4);
    ushort4 o;
    o.x = f2bf(v.x); o.y = f2bf(v.y); o.z = f2bf(v.z); o.w = f2bf(v.w);
    *reinterpret_cast<ushort4*>(Xbf + i * 4) = o;
    return;
  }

  __shared__ float tile[32][33];
  const float* in;
  unsigned short* out;
  int Kd, Nd, n0, k0;
  if (b < 4096) {              // W1: Kd=1024 (H), Nd=4096 (I)
    in = W1; out = W1t; Kd = 1024; Nd = 4096;
    n0 = (b & 127) * 32;
    k0 = (b >> 7) * 32;
  } else {                     // W2: Kd=4096 (I), Nd=1024 (H)
    const int b2 = b - 4096;
    in = W2; out = W2t; Kd = 4096; Nd = 1024;
    n0 = (b2 & 31) * 32;
    k0 = (b2 >> 5) * 32;
  }
  const int tx = tid & 31;
  const int ty = tid >> 5;
#pragma unroll
  for (int i = 0; i < 4; ++i)
    tile[ty + i * 8][tx] = in[(size_t)(k0 + ty + i * 8) * Nd + n0 + tx];
  __syncthreads();
#pragma unroll
  for (int i = 0; i < 4; ++i)
    out[(size_t)(n0 + ty + i * 8) * Kd + k0 + tx] = f2bf(tile[tx][ty + i * 8]);
}

// ---------------------------------------------------------------------------
// Standalone prep kernels (fallback path only).
// ---------------------------------------------------------------------------
__global__ void cvt_f32_bf16(const float* __restrict__ in,
                             unsigned short* __restrict__ out, int n4) {
  int i = blockIdx.x * blockDim.x + threadIdx.x;
  if (i >= n4) return;
  float4 v = *reinterpret_cast<const float4*>(in + (size_t)i * 4);
  ushort4 o;
  o.x = f2bf(v.x); o.y = f2bf(v.y); o.z = f2bf(v.z); o.w = f2bf(v.w);
  *reinterpret_cast<ushort4*>(out + (size_t)i * 4) = o;
}

__global__ void transpose_cvt(const float* __restrict__ in,
                              unsigned short* __restrict__ out,
                              int Kd, int Nd) {
  __shared__ float tile[32][33];
  const int n0 = blockIdx.x * 32;
  const int k0 = blockIdx.y * 32;
  const int tx = threadIdx.x;
  const int ty = threadIdx.y;
#pragma unroll
  for (int i = 0; i < 4; ++i)
    tile[ty + i * 8][tx] = in[(size_t)(k0 + ty + i * 8) * Nd + n0 + tx];
  __syncthreads();
#pragma unroll
  for (int i = 0; i < 4; ++i)
    out[(size_t)(n0 + ty + i * 8) * Kd + k0 + tx] = f2bf(tile[tx][ty + i * 8]);
}

// ---------------------------------------------------------------------------
// QUADRANT-PHASE GEMM (round-13, best verified: 157.2us total, GEMMs ~906TF,
// FETCH/WRITE ~= compulsory, 0 bank conflicts):
// 256xBN tile, 8 waves, BK=64. Phase = C-quadrant (QM,QN) over full K=64 ->
// phase p needs ONLY A-half QM and B-half QN; halves staged 3-4 phases
// ahead; uniform counted waits {2LA, LA+LB, 2LB, LB+LA}; fragment reads at
// PHASE START, strictly after the vwait-then-barrier pair (collective
// completion guarantee — r14/r16 read-ahead variants were racy or slower).
// Swizzle a^=((a>>7)&7)<<4 both sides (0-conflict); coalesced bounce
// epilogue (r12, -11us verified).
// ---------------------------------------------------------------------------
#define QPH(D, QM, QN, RDA, RDB, STAGE, WAITC)                                 \
  {                                                                            \
    if (RDA) {                                                                 \
      char* ab = lds + (D) * 32768 + (QM) * 16384;                             \
      _Pragma("unroll")                                                        \
      for (int mi = 0; mi < 4; ++mi)                                           \
        _Pragma("unroll")                                                      \
        for (int kk = 0; kk < 2; ++kk)                                         \
          aF[mi][kk] = *reinterpret_cast<const short8*>(ab + ardA[mi][kk]);    \
    }                                                                          \
    if (RDB) {                                                                 \
      char* bb = lds + 65536 + (D) * 2 * BHB + (QN) * BHB;                     \
      _Pragma("unroll")                                                        \
      for (int ni = 0; ni < NF; ++ni)                                          \
        _Pragma("unroll")                                                      \
        for (int kk = 0; kk < 2; ++kk)                                         \
          bF[QN][ni][kk] = *reinterpret_cast<const short8*>(bb + brdB[ni][kk]);\
    }                                                                          \
    STAGE;                                                                     \
    __builtin_amdgcn_s_setprio(1);                                             \
    _Pragma("unroll")                                                          \
    for (int mi = 0; mi < 4; ++mi)                                             \
      _Pragma("unroll")                                                        \
      for (int ni = 0; ni < NF; ++ni)                                          \
        _Pragma("unroll")                                                      \
        for (int kk = 0; kk < 2; ++kk)                                         \
          acc[QM][QN][mi][ni] = __builtin_amdgcn_mfma_f32_16x16x32_bf16(       \
              aF[mi][kk], bF[QN][ni][kk], acc[QM][QN][mi][ni], 0, 0, 0);       \
    __builtin_amdgcn_s_setprio(0);                                             \
    WAITC;                                                                     \
    __builtin_amdgcn_s_barrier();                                              \
  }

template <int BN, int RELU_BF16_OUT>
__global__ __launch_bounds__(512, 2)
void gemm_q(const unsigned short* __restrict__ A, int lda,
            const unsigned short* __restrict__ B, int ldb,
            const float* __restrict__ bias,
            void* __restrict__ C, int ldc, int K, int nbx) {
  constexpr int NF  = BN / 128;        // B frags per wave per quadrant (2/1)
  constexpr int LA  = 2;               // loads/thread per A-half stage
  constexpr int LB  = BN / 128;        // loads/thread per B-half stage (2/1)
  constexpr int BHB = BN * 64;         // bytes per B half-buffer (16K/8K)
  extern __shared__ char lds[];

  const int tid  = threadIdx.x;
  const int lane = tid & 63;
  const int wid  = tid >> 6;
  const int wm2  = wid >> 2;   // 0..1 (64-row slice within 128-row quadrant)
  const int wn4  = wid & 3;    // 0..3 (col slice within quadrant)

  // bijective XCD-chunked swizzle (grid % 8 == 0)
  const int cpx     = gridDim.x >> 3;
  const int logical = (blockIdx.x & 7) * cpx + (blockIdx.x >> 3);
  const int m0 = (logical / nbx) * 256;
  const int n0 = (logical % nbx) * BN;

  f32x4 acc[2][2][4][NF];
#pragma unroll
  for (int a = 0; a < 2; ++a)
#pragma unroll
    for (int b = 0; b < 2; ++b)
#pragma unroll
      for (int c = 0; c < 4; ++c)
#pragma unroll
        for (int d = 0; d < NF; ++d)
          acc[a][b][c][d] = (f32x4){0.f, 0.f, 0.f, 0.f};

  // stage maps: linear LDS dest, pre-swizzled global source.
  size_t aG[2], bG[2];
#pragma unroll
  for (int u = 0; u < 2; ++u) {
    const int s   = (u * 512 + tid) * 16;
    const int nat = s ^ (((s >> 7) & 7) << 4);
    aG[u] = (size_t)(m0 + (nat >> 7)) * lda + ((nat & 127) >> 1);
    if (u < LB)
      bG[u] = (size_t)(n0 + (nat >> 7)) * ldb + ((nat & 127) >> 1);
    else
      bG[u] = 0;
  }
  const int wb0 = (tid & 448) * 16;    // wave-uniform base (+lane*16 by HW)
  const int wb1 = 8192 + wb0;

  auto stageA = [&](int d, int h, int kel) {
    char* dst = lds + d * 32768 + h * 16384;
    gload_lds16(A + aG[0] + (size_t)h * 128 * lda + kel, dst + wb0);
    gload_lds16(A + aG[1] + (size_t)h * 128 * lda + kel, dst + wb1);
  };
  auto stageB = [&](int d, int h, int kel) {
    char* dst = lds + 65536 + d * 2 * BHB + h * BHB;
    gload_lds16(B + bG[0] + (size_t)h * (BN / 2) * ldb + kel, dst + wb0);
    if constexpr (LB == 2)
      gload_lds16(B + bG[1] + (size_t)h * (BN / 2) * ldb + kel, dst + wb1);
  };

  // swizzled ds_read offsets (within one half-buffer)
  int ardA[4][2], brdB[NF][2];
#pragma unroll
  for (int mi = 0; mi < 4; ++mi)
#pragma unroll
    for (int kk = 0; kk < 2; ++kk) {
      const int nat = (wm2 * 64 + mi * 16 + (lane & 15)) * 128 +
                      kk * 64 + (lane >> 4) * 16;
      ardA[mi][kk] = nat ^ (((nat >> 7) & 7) << 4);
    }
#pragma unroll
  for (int ni = 0; ni < NF; ++ni)
#pragma unroll
    for (int kk = 0; kk < 2; ++kk) {
      const int nat = (wn4 * (BN / 8) + ni * 16 + (lane & 15)) * 128 +
                      kk * 64 + (lane >> 4) * 16;
      brdB[ni][kk] = nat ^ (((nat >> 7) & 7) << 4);
    }

  // prologue: tile 0 halves in order [A0, B0, B1, A1]; leave B1,A1 in flight
  stageA(0, 0, 0);
  stageB(0, 0, 0);
  stageB(0, 1, 0);
  stageA(0, 1, 0);
  vwait<LA + LB>();
  __builtin_amdgcn_s_barrier();

  short8 aF[4][2];
  short8 bF[2][NF][2];
  const int NT = K >> 6;
  for (int it = 0; it < NT - 1; ++it) {
    const int d = it & 1, e = d ^ 1;
    const int nk = (it + 1) << 6;
    QPH(d, 0, 0, 1, 1, stageA(e, 0, nk), vwait<2 * LA>());
    QPH(d, 0, 1, 0, 1, stageB(e, 0, nk), (vwait<LA + LB>()));
    QPH(d, 1, 0, 1, 0, stageB(e, 1, nk), vwait<2 * LB>());
    QPH(d, 1, 1, 0, 0, stageA(e, 1, nk), (vwait<LB + LA>()));
  }
  {
    const int d = (NT - 1) & 1;
    QPH(d, 0, 0, 1, 1, ((void)0), vwait<LA>());
    QPH(d, 0, 1, 0, 1, ((void)0), vwait<0>());
    QPH(d, 1, 0, 1, 0, ((void)0), ((void)0));
    QPH(d, 1, 1, 0, 0, ((void)0), ((void)0));
  }

  // ---- Coalesced epilogue via LDS bounce (r12, verified) -----------------
  __syncthreads();
  {
#pragma unroll
    for (int qm = 0; qm < 2; ++qm) {
#pragma unroll
      for (int qn = 0; qn < 2; ++qn) {
#pragma unroll
        for (int ni = 0; ni < NF; ++ni) {
          const int c = qn * (BN / 2) + wn4 * (BN / 8) + ni * 16 + (lane & 15);
          const float bv = bias[n0 + c];
#pragma unroll
          for (int mi = 0; mi < 4; ++mi) {
#pragma unroll
            for (int rr = 0; rr < 4; ++rr) {
              const int row = qm * 128 + wm2 * 64 + mi * 16 +
                              (lane >> 4) * 4 + rr;
              float v = acc[qm][qn][mi][ni][rr] + bv;
              if (RELU_BF16_OUT) {
                v = v > 0.f ? v : 0.f;
                const int byte = (row * 512 + c * 2) ^ ((row & 7) << 4);
                *reinterpret_cast<unsigned short*>(lds + byte) = f2bf(v);
              } else {
                const int byte = (row * 512 + c * 4) ^ ((row & 7) << 4);
                *reinterpret_cast<float*>(lds + byte) = v;
              }
            }
          }
        }
      }
    }
    __syncthreads();
#pragma unroll
    for (int i = 0; i < 16; ++i) {
      const int idx  = i * 512 + tid;        // 0..8191
      const int row  = idx >> 5;
      const int g    = idx & 31;
      const int byte = (row * 512 + g * 16) ^ ((row & 7) << 4);
      const uint4 val = *reinterpret_cast<const uint4*>(lds + byte);
      if (RELU_BF16_OUT) {
        unsigned short* dst = (unsigned short*)C +
            (size_t)(m0 + row) * ldc + n0 + g * 8;
        *reinterpret_cast<uint4*>(dst) = val;
      } else {
        float* dst = (float*)C + (size_t)(m0 + row) * ldc + n0 + g * 4;
        *reinterpret_cast<uint4*>(dst) = val;
      }
    }
  }
}

// ---------------------------------------------------------------------------
// Fallback 128^2 GEMM (round-2, verified) for small-ws configurations.
// ---------------------------------------------------------------------------
template <int A_F32, int RELU_BF16_OUT>
__global__ __launch_bounds__(256, 2)
void gemm_bf16(const void* __restrict__ Ap, int lda,
               const unsigned short* __restrict__ B, int ldb,
               const float* __restrict__ bias,
               void* __restrict__ C, int ldc,
               int K, int beta) {
  __shared__ char lds[32768];
  char* const As = lds;
  char* const Bs = lds + 16384;

  const int tid  = threadIdx.x;
  const int lane = tid & 63;
  const int w    = tid >> 6;
  const int wm   = w >> 1;
  const int wn   = w & 1;
  const int m0   = blockIdx.y * 128;
  const int n0   = blockIdx.x * 128;

  f32x4 acc[4][4];
#pragma unroll
  for (int i = 0; i < 4; ++i)
#pragma unroll
    for (int j = 0; j < 4; ++j)
      acc[i][j] = (f32x4){0.f, 0.f, 0.f, 0.f};

  int srow[4], scol[4], sbase[4];
#pragma unroll
  for (int j = 0; j < 4; ++j) {
    const int stored  = (j * 256 + tid) * 16;
    const int natural = stored ^ (((stored >> 7) & 7) << 4);
    srow[j]  = natural >> 7;
    scol[j]  = (natural & 127) >> 1;
    sbase[j] = (j * 256 + (tid & 192)) * 16;
  }

  size_t agofs[4];
  int ast[4];
  if (A_F32) {
#pragma unroll
    for (int pq = 0; pq < 4; ++pq) {
      const int idx = pq * 256 + tid;
      const int rr  = idx >> 3;
      const int kbe = (idx & 7) * 8;
      agofs[pq] = (size_t)(m0 + rr) * lda + kbe;
      const int nat = rr * 128 + kbe * 2;
      ast[pq] = nat ^ (((nat >> 7) & 7) << 4);
    }
  }

  const int nsteps = K >> 6;
  for (int ks = 0; ks < nsteps; ++ks) {
    const int k0 = ks << 6;
    if (A_F32) {
      const float* Af = (const float*)Ap;
#pragma unroll
      for (int pq = 0; pq < 4; ++pq) {
        const float* sp = Af + agofs[pq] + k0;
        float4 x0 = *reinterpret_cast<const float4*>(sp);
        float4 x1 = *reinterpret_cast<const float4*>(sp + 4);
        ushort8 v;
        v[0] = f2bf(x0.x); v[1] = f2bf(x0.y); v[2] = f2bf(x0.z); v[3] = f2bf(x0.w);
        v[4] = f2bf(x1.x); v[5] = f2bf(x1.y); v[6] = f2bf(x1.z); v[7] = f2bf(x1.w);
        *reinterpret_cast<ushort8*>(As + ast[pq]) = v;
      }
    } else {
      const unsigned short* Ab = (const unsigned short*)Ap;
#pragma unroll
      for (int j = 0; j < 4; ++j)
        gload_lds16(Ab + (size_t)(m0 + srow[j]) * lda + (k0 + scol[j]),
                    As + sbase[j]);
    }
#pragma unroll
    for (int j = 0; j < 4; ++j)
      gload_lds16(B + (size_t)(n0 + srow[j]) * ldb + (k0 + scol[j]),
                  Bs + sbase[j]);
    __syncthreads();

#pragma unroll
    for (int kk = 0; kk < 2; ++kk) {
      const int kb = kk * 64 + (lane >> 4) * 16;
      short8 af[4], bfv[4];
#pragma unroll
      for (int mi = 0; mi < 4; ++mi) {
        int nat = (wm * 64 + mi * 16 + (lane & 15)) * 128 + kb;
        int st  = nat ^ (((nat >> 7) & 7) << 4);
        af[mi] = *reinterpret_cast<const short8*>(As + st);
      }
#pragma unroll
      for (int ni = 0; ni < 4; ++ni) {
        int nat = (wn * 64 + ni * 16 + (lane & 15)) * 128 + kb;
        int st  = nat ^ (((nat >> 7) & 7) << 4);
        bfv[ni] = *reinterpret_cast<const short8*>(Bs + st);
      }
#pragma unroll
      for (int mi = 0; mi < 4; ++mi)
#pragma unroll
        for (int ni = 0; ni < 4; ++ni)
          acc[mi][ni] = __builtin_amdgcn_mfma_f32_16x16x32_bf16(
              af[mi], bfv[ni], acc[mi][ni], 0, 0, 0);
    }
    __syncthreads();
  }

  const int row0 = m0 + wm * 64 + (lane >> 4) * 4;
  const int col0 = n0 + wn * 64 + (lane & 15);
#pragma unroll
  for (int ni = 0; ni < 4; ++ni) {
    const int c = col0 + ni * 16;
    const float bv = beta ? 0.f : bias[c];
#pragma unroll
    for (int mi = 0; mi < 4; ++mi) {
#pragma unroll
      for (int rr = 0; rr < 4; ++rr) {
        const size_t idx = (size_t)(row0 + mi * 16 + rr) * ldc + c;
        float v = acc[mi][ni][rr] + bv;
        if (RELU_BF16_OUT) {
          v = v > 0.f ? v : 0.f;
          ((unsigned short*)C)[idx] = f2bf(v);
        } else {
          if (beta) v += ((float*)C)[idx];
          ((float*)C)[idx] = v;
        }
      }
    }
  }
}

// ---------------------------------------------------------------------------
extern "C" void kernel_launch(void* const* d_in, const int* in_sizes, int n_in,
                              void* d_out, int out_size, void* d_ws, size_t ws_size,
                              hipStream_t stream) {
  const float* X  = (const float*)d_in[0];  // [8192][1024]
  const float* W1 = (const float*)d_in[1];  // [1024][4096]
  const float* b1 = (const float*)d_in[2];  // [4096]
  const float* W2 = (const float*)d_in[3];  // [4096][1024]
  const float* b2 = (const float*)d_in[4];  // [1024]
  float* out = (float*)d_out;               // [8192][1024] f32

  const int M = 8192, H = 1024, I = 4096;
  const size_t MB = 1024 * 1024;

  char* ws = (char*)d_ws;
  unsigned short* W1t = (unsigned short*)ws;            // [I][H] bf16, 8 MB
  unsigned short* W2t = (unsigned short*)(ws + 8 * MB); // [H][I] bf16, 8 MB

  if (ws_size >= 80 * MB) {
    // Fast path. Xbf parked in d_out tail (fully consumed by L1 before the
    // single L2 dispatch writes d_out; stream-serialized).
    unsigned short* Xbf = (unsigned short*)((char*)d_out + 16 * MB);
    unsigned short* Hbf = (unsigned short*)(ws + 16 * MB);   // [M][I] bf16
    prep_fused<<<16384, 256, 0, stream>>>(X, W1, W2, Xbf, W1t, W2t);
    // L1: Hbf = relu(X*W1+b1). quadrant-phase 256x256, grid 512, 128 KiB.
    gemm_q<256, 1><<<512, 512, 131072, stream>>>(
        Xbf, H, W1t, H, b1, Hbf, I, H, I / 256);
    // L2: out = Hbf*W2+b2. quadrant-phase 256x128, grid 256, 128 KiB.
    gemm_q<128, 0><<<256, 512, 131072, stream>>>(
        Hbf, I, W2t, I, b2, out, H, I, H / 128);
    return;
  }

  // Fallback: adaptive chunked path (round-2 verified kernels).
  transpose_cvt<<<dim3(I / 32, H / 32), dim3(32, 8), 0, stream>>>(W1, W1t, H, I);
  transpose_cvt<<<dim3(H / 32, I / 32), dim3(32, 8), 0, stream>>>(W2, W2t, I, H);

  int Ic, useXbf;
  unsigned short* Xbf = nullptr;
  unsigned short* Hc;
  if (ws_size >= 64 * MB) {
    Ic = 2048; useXbf = 1;
    Xbf = (unsigned short*)(ws + 16 * MB);
    Hc  = (unsigned short*)(ws + 32 * MB);
  } else if (ws_size >= 48 * MB) {
    Ic = 1024; useXbf = 1;
    Xbf = (unsigned short*)(ws + 16 * MB);
    Hc  = (unsigned short*)(ws + 32 * MB);
  } else if (ws_size >= 32 * MB) {
    Ic = 1024; useXbf = 0;
    Hc  = (unsigned short*)(ws + 16 * MB);
  } else if (ws_size >= 24 * MB) {
    Ic = 512;  useXbf = 0;
    Hc  = (unsigned short*)(ws + 16 * MB);
  } else if (ws_size >= 20 * MB) {
    Ic = 256;  useXbf = 0;
    Hc  = (unsigned short*)(ws + 16 * MB);
  } else {
    Ic = 128;  useXbf = 0;
    Hc  = (unsigned short*)(ws + 16 * MB);
  }

  if (useXbf) {
    int n4 = (M * H) / 4;
    cvt_f32_bf16<<<(n4 + 255) / 256, 256, 0, stream>>>(X, Xbf, n4);
  }

  const int nch = I / Ic;
  for (int c = 0; c < nch; ++c) {
    const int i0 = c * Ic;
    if (useXbf)
      gemm_bf16<0, 1><<<dim3(Ic / 128, M / 128), 256, 0, stream>>>(
          Xbf, H, W1t + (size_t)i0 * H, H, b1 + i0, Hc, Ic, H, 0);
    else
      gemm_bf16<1, 1><<<dim3(Ic / 128, M / 128), 256, 0, stream>>>(
          X, H, W1t + (size_t)i0 * H, H, b1 + i0, Hc, Ic, H, 0);
    gemm_bf16<0, 0><<<dim3(H / 128, M / 128), 256, 0, stream>>>(
        Hc, Ic, W2t + i0, I, b2, out, H, Ic, c > 0);
  }
}